// Round 2
// baseline (110.013 us; speedup 1.0000x reference)
//
#include <hip/hip_runtime.h>
#include <stdint.h>

#define HH 4096
#define WW 4096
#define CC 3
#define NLOOP 1000

struct Desc {
  int psh, psw, ph, pw, wsh, wsw, pad0, pad1;
  unsigned long long mask, live;
  unsigned char src[3][64];
  unsigned char pad[16];
};
static_assert(sizeof(Desc) == 256, "desc size");

// JAX threefry2x32 (20 rounds), exact port of _threefry2x32_lowering.
__device__ __forceinline__ void tf2x32(uint32_t k0, uint32_t k1,
                                       uint32_t x0, uint32_t x1,
                                       uint32_t& o0, uint32_t& o1) {
  const uint32_t ks2 = k0 ^ k1 ^ 0x1BD11BDAu;
  x0 += k0; x1 += k1;
#define ROTL_(v,r) (((v)<<(r))|((v)>>(32-(r))))
#define RND_(r) { x0 += x1; x1 = ROTL_(x1,(r)); x1 ^= x0; }
  RND_(13) RND_(15) RND_(26) RND_(6)
  x0 += k1; x1 += ks2 + 1u;
  RND_(17) RND_(29) RND_(16) RND_(24)
  x0 += ks2; x1 += k0 + 2u;
  RND_(13) RND_(15) RND_(26) RND_(6)
  x0 += k0; x1 += k1 + 3u;
  RND_(17) RND_(29) RND_(16) RND_(24)
  x0 += k1; x1 += ks2 + 4u;
  RND_(13) RND_(15) RND_(26) RND_(6)
  x0 += ks2; x1 += k0 + 5u;
  o0 = x0; o1 = x1;
#undef RND_
#undef ROTL_
}

// 32-bit random_bits under partitionable threefry: XOR of the two output words.
__device__ __forceinline__ uint32_t rb32(uint32_t k0, uint32_t k1,
                                         uint32_t x0, uint32_t x1) {
  uint32_t o0, o1;
  tf2x32(k0, k1, x0, x1, o0, o1);
  return o0 ^ o1;
}

// One block (64 threads) per loop iteration: derive window + permutation.
// Partitionable-threefry semantics:
//   split(k,n)_t = tf(k,(0,t)) (both words form the new key)
//   random_bits(k,32,shape)[t] = xor of the two words of tf(k,(0,t))
//   randint span=8 -> 1 + (lower & 7), lower = rb32 of k2=split(kh,2)[1]
__global__ void k_desc(const int* __restrict__ seedp, Desc* __restrict__ d) {
  const int i = blockIdx.x;
  const int lane = threadIdx.x;
  const uint32_t K0 = 0u;
  const uint32_t K1 = (uint32_t)seedp[0];

  uint32_t k0, k1, a0, a1;
  tf2x32(K0, K1, 0u, (uint32_t)i, k0, k1);

  uint32_t kh0,kh1,kw0,kw1,kp0,kp1,kq0,kq1,kr0,kr1;
  tf2x32(k0,k1,0u,0u,kh0,kh1);   // kh
  tf2x32(k0,k1,0u,1u,kw0,kw1);   // kw
  tf2x32(k0,k1,0u,2u,kp0,kp1);   // kph
  tf2x32(k0,k1,0u,3u,kq0,kq1);   // kpw
  tf2x32(k0,k1,0u,4u,kr0,kr1);   // kperm

  tf2x32(kh0,kh1,0u,1u,a0,a1);   // k2 of randint's internal split
  const int wsh = 1 + (int)(rb32(a0,a1,0u,0u) & 7u);
  tf2x32(kw0,kw1,0u,1u,a0,a1);
  const int wsw = 1 + (int)(rb32(a0,a1,0u,0u) & 7u);

  const float uh = __uint_as_float(0x3F800000u | (rb32(kp0,kp1,0u,0u) >> 9)) - 1.0f;
  const float uw = __uint_as_float(0x3F800000u | (rb32(kq0,kq1,0u,0u) >> 9)) - 1.0f;

  const int ph = (int)(uh * (float)(HH - wsh + 1));
  const int pw = (int)(uw * (float)(WW - wsw + 1));
  const int psh = min(ph, HH - 8);
  const int psw = min(pw, WW - 8);
  const int offh = ph - psh;
  const int offw = pw - psw;

  // mask bit q=r*8+c set iff r in [offh,offh+wsh) and c in [offw,offw+wsw)
  const uint32_t colm = ((1u << wsw) - 1u) << offw;
  unsigned long long rows = (wsh == 8) ? ~0ull : ((1ull << (8 * wsh)) - 1ull);
  rows <<= (8 * offh);
  const unsigned long long mask =
      rows & (0x0101010101010101ull * (unsigned long long)colm);

  // 192 uniform draws for kperm: element t -> rb32(kperm,(0,t)), keep top 23 bits
  __shared__ uint32_t rb[CC * 64];
  for (int t = lane; t < CC * 64; t += 64) {
    rb[t] = rb32(kr0, kr1, 0u, (uint32_t)t) >> 9;  // monotone in float value
  }

  const bool masked = ((mask >> lane) & 1ull) != 0ull;
  __shared__ unsigned char mlist[64];   // j-th masked index (ascending)
  __shared__ unsigned char srcbuf[64];
  const int ordinal = __popcll(mask & ((lane == 0) ? 0ull : ((1ull << lane) - 1ull)));
  __syncthreads();                       // rb ready
  if (masked) mlist[ordinal] = (unsigned char)lane;

  for (int c = 0; c < CC; ++c) {
    // stable rank of this masked element among masked by (randbits, index)
    int rank = 0;
    if (masked) {
      const uint32_t myk = rb[(c << 6) | lane];
      for (int q = 0; q < 64; ++q) {
        if ((mask >> q) & 1ull) {
          const uint32_t kq = rb[(c << 6) | q];
          if (kq < myk || (kq == myk && q < lane)) ++rank;
        }
      }
    }
    srcbuf[lane] = (unsigned char)lane;
    __syncthreads();                     // also orders mlist write above
    if (masked) srcbuf[mlist[rank]] = (unsigned char)lane; // dest m_rank <- src lane
    __syncthreads();
    d[i].src[c][lane] = srcbuf[lane];
    __syncthreads();
  }

  if (lane == 0) {
    d[i].psh = psh; d[i].psw = psw; d[i].ph = ph; d[i].pw = pw;
    d[i].wsh = wsh; d[i].wsw = wsw; d[i].mask = mask;
    d[i].pad0 = 0; d[i].pad1 = 0;
  }
}

// live_i = mask_i minus coverage by any later window (last writer wins).
__global__ void k_live(Desc* __restrict__ d) {
  const int i = blockIdx.x;
  const int t = threadIdx.x;   // 64
  const int psh = d[i].psh, psw = d[i].psw;
  unsigned long long clr = 0ull;
  for (int j = i + 1 + t; j < NLOOP; j += 64) {
    const int phj = d[j].ph, pwj = d[j].pw;
    const int whj = d[j].wsh, wwj = d[j].wsw;
    const int r0 = max(0, phj - psh), r1 = min(8, phj + whj - psh);
    const int c0 = max(0, pwj - psw), c1 = min(8, pwj + wwj - psw);
    if (r0 < r1 && c0 < c1) {
      const uint32_t colm = ((1u << (c1 - c0)) - 1u) << c0;
      const int nr = r1 - r0;
      unsigned long long rows = (nr == 8) ? ~0ull : ((1ull << (8 * nr)) - 1ull);
      rows <<= (8 * r0);
      clr |= rows & (0x0101010101010101ull * (unsigned long long)colm);
    }
  }
  __shared__ unsigned long long sh[64];
  sh[t] = clr;
  __syncthreads();
  for (int s = 32; s > 0; s >>= 1) {
    if (t < s) sh[t] |= sh[t + s];
    __syncthreads();
  }
  if (t == 0) d[i].live = d[i].mask & ~sh[0];
}

__global__ void k_copy(const float4* __restrict__ in, float4* __restrict__ out, int n4) {
  int idx = blockIdx.x * blockDim.x + threadIdx.x;
  const int stride = gridDim.x * blockDim.x;
  for (int i = idx; i < n4; i += stride) out[i] = in[i];
}

// Scatter the shuffled values (sources always from the ORIGINAL image).
__global__ void k_apply(const float* __restrict__ in, float* __restrict__ out,
                        const Desc* __restrict__ d) {
  const int i = blockIdx.x;
  const int t = threadIdx.x;   // 192
  const int c = t >> 6, q = t & 63;
  const unsigned long long live = d[i].live;
  if ((live >> q) & 1ull) {
    const int psh = d[i].psh, psw = d[i].psw;
    const int s = d[i].src[c][q];
    const size_t base = (size_t)c * (size_t)HH * (size_t)WW;
    out[base + (size_t)(psh + (q >> 3)) * WW + (size_t)(psw + (q & 7))] =
        in[base + (size_t)(psh + (s >> 3)) * WW + (size_t)(psw + (s & 7))];
  }
}

extern "C" void kernel_launch(void* const* d_in, const int* in_sizes, int n_in,
                              void* d_out, int out_size, void* d_ws, size_t ws_size,
                              hipStream_t stream) {
  const float* img = (const float*)d_in[0];
  const int* seed = (const int*)d_in[1];
  float* out = (float*)d_out;
  Desc* d = (Desc*)d_ws;   // needs NLOOP*256 = 256 KiB

  hipLaunchKernelGGL(k_desc, dim3(NLOOP), dim3(64), 0, stream, seed, d);
  hipLaunchKernelGGL(k_live, dim3(NLOOP), dim3(64), 0, stream, d);
  const int n4 = (CC * HH * WW) / 4;
  hipLaunchKernelGGL(k_copy, dim3(2048), dim3(256), 0, stream,
                     (const float4*)img, (float4*)out, n4);
  hipLaunchKernelGGL(k_apply, dim3(NLOOP), dim3(192), 0, stream, img, out, d);
}

// Round 4
// 97.358 us; speedup vs baseline: 1.1300x; 1.1300x over previous
//
#include <hip/hip_runtime.h>
#include <stdint.h>

#define HH 4096
#define WW 4096
#define CC 3
#define NLOOP 1000

typedef float vfloat4 __attribute__((ext_vector_type(4)));

struct Desc {
  int psh, psw, ph, pw, wsh, wsw, pad0, pad1;
  unsigned long long mask, live;
  unsigned char src[3][64];
  unsigned char pad[16];
};
static_assert(sizeof(Desc) == 256, "desc size");

// JAX threefry2x32 (20 rounds), exact port of _threefry2x32_lowering.
__device__ __forceinline__ void tf2x32(uint32_t k0, uint32_t k1,
                                       uint32_t x0, uint32_t x1,
                                       uint32_t& o0, uint32_t& o1) {
  const uint32_t ks2 = k0 ^ k1 ^ 0x1BD11BDAu;
  x0 += k0; x1 += k1;
#define ROTL_(v,r) (((v)<<(r))|((v)>>(32-(r))))
#define RND_(r) { x0 += x1; x1 = ROTL_(x1,(r)); x1 ^= x0; }
  RND_(13) RND_(15) RND_(26) RND_(6)
  x0 += k1; x1 += ks2 + 1u;
  RND_(17) RND_(29) RND_(16) RND_(24)
  x0 += ks2; x1 += k0 + 2u;
  RND_(13) RND_(15) RND_(26) RND_(6)
  x0 += k0; x1 += k1 + 3u;
  RND_(17) RND_(29) RND_(16) RND_(24)
  x0 += k1; x1 += ks2 + 4u;
  RND_(13) RND_(15) RND_(26) RND_(6)
  x0 += ks2; x1 += k0 + 5u;
  o0 = x0; o1 = x1;
#undef RND_
#undef ROTL_
}

// 32-bit random_bits under partitionable threefry: XOR of the two output words.
__device__ __forceinline__ uint32_t rb32(uint32_t k0, uint32_t k1,
                                         uint32_t x0, uint32_t x1) {
  uint32_t o0, o1;
  tf2x32(k0, k1, x0, x1, o0, o1);
  return o0 ^ o1;
}

// One block (64 threads) per loop iteration: derive window + permutation.
__global__ void k_desc(const int* __restrict__ seedp, Desc* __restrict__ d) {
  const int i = blockIdx.x;
  const int lane = threadIdx.x;
  const uint32_t K0 = 0u;
  const uint32_t K1 = (uint32_t)seedp[0];

  uint32_t k0, k1, a0, a1;
  tf2x32(K0, K1, 0u, (uint32_t)i, k0, k1);

  uint32_t kh0,kh1,kw0,kw1,kp0,kp1,kq0,kq1,kr0,kr1;
  tf2x32(k0,k1,0u,0u,kh0,kh1);   // kh
  tf2x32(k0,k1,0u,1u,kw0,kw1);   // kw
  tf2x32(k0,k1,0u,2u,kp0,kp1);   // kph
  tf2x32(k0,k1,0u,3u,kq0,kq1);   // kpw
  tf2x32(k0,k1,0u,4u,kr0,kr1);   // kperm

  tf2x32(kh0,kh1,0u,1u,a0,a1);   // k2 of randint's internal split
  const int wsh = 1 + (int)(rb32(a0,a1,0u,0u) & 7u);
  tf2x32(kw0,kw1,0u,1u,a0,a1);
  const int wsw = 1 + (int)(rb32(a0,a1,0u,0u) & 7u);

  const float uh = __uint_as_float(0x3F800000u | (rb32(kp0,kp1,0u,0u) >> 9)) - 1.0f;
  const float uw = __uint_as_float(0x3F800000u | (rb32(kq0,kq1,0u,0u) >> 9)) - 1.0f;

  const int ph = (int)(uh * (float)(HH - wsh + 1));
  const int pw = (int)(uw * (float)(WW - wsw + 1));
  const int psh = min(ph, HH - 8);
  const int psw = min(pw, WW - 8);
  const int offh = ph - psh;
  const int offw = pw - psw;

  const uint32_t colm = ((1u << wsw) - 1u) << offw;
  unsigned long long rows = (wsh == 8) ? ~0ull : ((1ull << (8 * wsh)) - 1ull);
  rows <<= (8 * offh);
  const unsigned long long mask =
      rows & (0x0101010101010101ull * (unsigned long long)colm);

  __shared__ uint32_t rb[CC * 64];
  for (int t = lane; t < CC * 64; t += 64) {
    rb[t] = rb32(kr0, kr1, 0u, (uint32_t)t) >> 9;  // monotone in float value
  }

  const bool masked = ((mask >> lane) & 1ull) != 0ull;
  __shared__ unsigned char mlist[64];
  __shared__ unsigned char srcbuf[64];
  const int ordinal = __popcll(mask & ((lane == 0) ? 0ull : ((1ull << lane) - 1ull)));
  __syncthreads();                       // rb ready
  if (masked) mlist[ordinal] = (unsigned char)lane;

  for (int c = 0; c < CC; ++c) {
    int rank = 0;
    if (masked) {
      const uint32_t myk = rb[(c << 6) | lane];
      for (int q = 0; q < 64; ++q) {
        if ((mask >> q) & 1ull) {
          const uint32_t kq = rb[(c << 6) | q];
          if (kq < myk || (kq == myk && q < lane)) ++rank;
        }
      }
    }
    srcbuf[lane] = (unsigned char)lane;
    __syncthreads();
    if (masked) srcbuf[mlist[rank]] = (unsigned char)lane;
    __syncthreads();
    d[i].src[c][lane] = srcbuf[lane];
    __syncthreads();
  }

  if (lane == 0) {
    d[i].psh = psh; d[i].psw = psw; d[i].ph = ph; d[i].pw = pw;
    d[i].wsh = wsh; d[i].wsw = wsw; d[i].mask = mask;
    d[i].pad0 = 0; d[i].pad1 = 0;
  }
}

// Streaming copy: nontemporal hints (read-once / write-once, skip L2 reuse).
__global__ void k_copy(const vfloat4* __restrict__ in, vfloat4* __restrict__ out, int n4) {
  int idx = blockIdx.x * blockDim.x + threadIdx.x;
  const int stride = gridDim.x * blockDim.x;
  for (int i = idx; i < n4; i += stride) {
    vfloat4 v = __builtin_nontemporal_load(&in[i]);
    __builtin_nontemporal_store(v, &out[i]);
  }
}

// Fused: live_i = mask_i minus coverage by later windows; then scatter window i.
__global__ void k_live_apply(const float* __restrict__ in, float* __restrict__ out,
                             Desc* __restrict__ d) {
  const int i = blockIdx.x;
  const int t = threadIdx.x;   // 64
  const int psh = d[i].psh, psw = d[i].psw;
  unsigned long long clr = 0ull;
  for (int j = i + 1 + t; j < NLOOP; j += 64) {
    const int phj = d[j].ph, pwj = d[j].pw;
    const int whj = d[j].wsh, wwj = d[j].wsw;
    const int r0 = max(0, phj - psh), r1 = min(8, phj + whj - psh);
    const int c0 = max(0, pwj - psw), c1 = min(8, pwj + wwj - psw);
    if (r0 < r1 && c0 < c1) {
      const uint32_t colm = ((1u << (c1 - c0)) - 1u) << c0;
      const int nr = r1 - r0;
      unsigned long long rows = (nr == 8) ? ~0ull : ((1ull << (8 * nr)) - 1ull);
      rows <<= (8 * r0);
      clr |= rows & (0x0101010101010101ull * (unsigned long long)colm);
    }
  }
  __shared__ unsigned long long sh[64];
  sh[t] = clr;
  __syncthreads();
  for (int s = 32; s > 0; s >>= 1) {
    if (t < s) sh[t] |= sh[t + s];
    __syncthreads();
  }
  const unsigned long long live = d[i].mask & ~sh[0];

  // scatter: sources always from the ORIGINAL image (copy already done)
  const int q = t;
  if ((live >> q) & 1ull) {
    const int row = psh + (q >> 3), col = psw + (q & 7);
    #pragma unroll
    for (int c = 0; c < CC; ++c) {
      const int s = d[i].src[c][q];
      const size_t base = (size_t)c * (size_t)HH * (size_t)WW;
      out[base + (size_t)row * WW + (size_t)col] =
          in[base + (size_t)(psh + (s >> 3)) * WW + (size_t)(psw + (s & 7))];
    }
  }
}

extern "C" void kernel_launch(void* const* d_in, const int* in_sizes, int n_in,
                              void* d_out, int out_size, void* d_ws, size_t ws_size,
                              hipStream_t stream) {
  const float* img = (const float*)d_in[0];
  const int* seed = (const int*)d_in[1];
  float* out = (float*)d_out;
  Desc* d = (Desc*)d_ws;   // needs NLOOP*256 = 256 KiB

  hipLaunchKernelGGL(k_desc, dim3(NLOOP), dim3(64), 0, stream, seed, d);
  const int n4 = (CC * HH * WW) / 4;
  hipLaunchKernelGGL(k_copy, dim3(4096), dim3(256), 0, stream,
                     (const vfloat4*)img, (vfloat4*)out, n4);
  hipLaunchKernelGGL(k_live_apply, dim3(NLOOP), dim3(64), 0, stream, img, out, d);
}

// Round 5
// 78.407 us; speedup vs baseline: 1.4031x; 1.2417x over previous
//
#include <hip/hip_runtime.h>
#include <stdint.h>

#define HH 4096
#define WW 4096
#define CC 3
#define NLOOP 1000
#define NCOPY 8192   // copy blocks in the merged kernel

typedef float vfloat4 __attribute__((ext_vector_type(4)));

struct Desc {
  int psh, psw, ph, pw, wsh, wsw, pad0, pad1;
  unsigned long long mask, live;
  unsigned char src[3][64];
  unsigned char pad[16];
};
static_assert(sizeof(Desc) == 256, "desc size");

// JAX threefry2x32 (20 rounds), exact port of _threefry2x32_lowering.
__device__ __forceinline__ void tf2x32(uint32_t k0, uint32_t k1,
                                       uint32_t x0, uint32_t x1,
                                       uint32_t& o0, uint32_t& o1) {
  const uint32_t ks2 = k0 ^ k1 ^ 0x1BD11BDAu;
  x0 += k0; x1 += k1;
#define ROTL_(v,r) (((v)<<(r))|((v)>>(32-(r))))
#define RND_(r) { x0 += x1; x1 = ROTL_(x1,(r)); x1 ^= x0; }
  RND_(13) RND_(15) RND_(26) RND_(6)
  x0 += k1; x1 += ks2 + 1u;
  RND_(17) RND_(29) RND_(16) RND_(24)
  x0 += ks2; x1 += k0 + 2u;
  RND_(13) RND_(15) RND_(26) RND_(6)
  x0 += k0; x1 += k1 + 3u;
  RND_(17) RND_(29) RND_(16) RND_(24)
  x0 += k1; x1 += ks2 + 4u;
  RND_(13) RND_(15) RND_(26) RND_(6)
  x0 += ks2; x1 += k0 + 5u;
  o0 = x0; o1 = x1;
#undef RND_
#undef ROTL_
}

// 32-bit random_bits under partitionable threefry: XOR of the two output words.
__device__ __forceinline__ uint32_t rb32(uint32_t k0, uint32_t k1,
                                         uint32_t x0, uint32_t x1) {
  uint32_t o0, o1;
  tf2x32(k0, k1, x0, x1, o0, o1);
  return o0 ^ o1;
}

// Merged kernel: blocks [0,NLOOP) derive window descriptors (64 active lanes
// of a 256-thread block); blocks [NLOOP, NLOOP+NCOPY) stream-copy img->out.
// The two halves touch disjoint data, so they overlap in one dispatch.
__global__ __launch_bounds__(256) void k_desc_copy(
    const int* __restrict__ seedp, Desc* __restrict__ d,
    const vfloat4* __restrict__ in4, vfloat4* __restrict__ out4, int n4) {
  const int b = blockIdx.x;
  if (b >= NLOOP) {
    // ---- copy path ----
    int idx = (b - NLOOP) * 256 + threadIdx.x;
    const int stride = NCOPY * 256;
    for (int i = idx; i < n4; i += stride) {
      vfloat4 v = __builtin_nontemporal_load(&in4[i]);
      __builtin_nontemporal_store(v, &out4[i]);
    }
    return;
  }

  // ---- desc path (lanes 0..63 active for the scalar chain) ----
  const int i = b;
  const int tid = threadIdx.x;
  const int lane = tid & 63;
  const uint32_t K0 = 0u;
  const uint32_t K1 = (uint32_t)seedp[0];

  __shared__ uint32_t rb[CC * 64];
  __shared__ unsigned char mlist[64];
  __shared__ unsigned char srcbuf[64];

  uint32_t k0, k1, a0, a1;
  tf2x32(K0, K1, 0u, (uint32_t)i, k0, k1);

  uint32_t kh0,kh1,kw0,kw1,kp0,kp1,kq0,kq1,kr0,kr1;
  tf2x32(k0,k1,0u,0u,kh0,kh1);   // kh
  tf2x32(k0,k1,0u,1u,kw0,kw1);   // kw
  tf2x32(k0,k1,0u,2u,kp0,kp1);   // kph
  tf2x32(k0,k1,0u,3u,kq0,kq1);   // kpw
  tf2x32(k0,k1,0u,4u,kr0,kr1);   // kperm

  // 192 uniform draws for kperm, filled by threads 0..191 in one shot
  if (tid < CC * 64) rb[tid] = rb32(kr0, kr1, 0u, (uint32_t)tid) >> 9;

  tf2x32(kh0,kh1,0u,1u,a0,a1);   // k2 of randint's internal split
  const int wsh = 1 + (int)(rb32(a0,a1,0u,0u) & 7u);
  tf2x32(kw0,kw1,0u,1u,a0,a1);
  const int wsw = 1 + (int)(rb32(a0,a1,0u,0u) & 7u);

  const float uh = __uint_as_float(0x3F800000u | (rb32(kp0,kp1,0u,0u) >> 9)) - 1.0f;
  const float uw = __uint_as_float(0x3F800000u | (rb32(kq0,kq1,0u,0u) >> 9)) - 1.0f;

  const int ph = (int)(uh * (float)(HH - wsh + 1));
  const int pw = (int)(uw * (float)(WW - wsw + 1));
  const int psh = min(ph, HH - 8);
  const int psw = min(pw, WW - 8);
  const int offh = ph - psh;
  const int offw = pw - psw;

  const uint32_t colm = ((1u << wsw) - 1u) << offw;
  unsigned long long rows = (wsh == 8) ? ~0ull : ((1ull << (8 * wsh)) - 1ull);
  rows <<= (8 * offh);
  const unsigned long long mask =
      rows & (0x0101010101010101ull * (unsigned long long)colm);

  const bool masked = (tid < 64) && (((mask >> lane) & 1ull) != 0ull);
  const int ordinal = __popcll(mask & ((lane == 0) ? 0ull : ((1ull << lane) - 1ull)));
  __syncthreads();                       // rb ready
  if (masked) mlist[ordinal] = (unsigned char)lane;

  for (int c = 0; c < CC; ++c) {
    int rank = 0;
    if (masked) {
      const uint32_t myk = rb[(c << 6) | lane];
      for (int q = 0; q < 64; ++q) {
        if ((mask >> q) & 1ull) {
          const uint32_t kq = rb[(c << 6) | q];
          if (kq < myk || (kq == myk && q < lane)) ++rank;
        }
      }
    }
    if (tid < 64) srcbuf[lane] = (unsigned char)lane;
    __syncthreads();
    if (masked) srcbuf[mlist[rank]] = (unsigned char)lane;
    __syncthreads();
    if (tid < 64) d[i].src[c][lane] = srcbuf[lane];
    __syncthreads();
  }

  if (tid == 0) {
    d[i].psh = psh; d[i].psw = psw; d[i].ph = ph; d[i].pw = pw;
    d[i].wsh = wsh; d[i].wsw = wsw; d[i].mask = mask;
    d[i].pad0 = 0; d[i].pad1 = 0;
  }
}

// Fused: live_i = mask_i minus coverage by later windows; then scatter window i.
__global__ void k_live_apply(const float* __restrict__ in, float* __restrict__ out,
                             Desc* __restrict__ d) {
  const int i = blockIdx.x;
  const int t = threadIdx.x;   // 64
  const int psh = d[i].psh, psw = d[i].psw;
  unsigned long long clr = 0ull;
  for (int j = i + 1 + t; j < NLOOP; j += 64) {
    const int phj = d[j].ph, pwj = d[j].pw;
    const int whj = d[j].wsh, wwj = d[j].wsw;
    const int r0 = max(0, phj - psh), r1 = min(8, phj + whj - psh);
    const int c0 = max(0, pwj - psw), c1 = min(8, pwj + wwj - psw);
    if (r0 < r1 && c0 < c1) {
      const uint32_t colm = ((1u << (c1 - c0)) - 1u) << c0;
      const int nr = r1 - r0;
      unsigned long long rows = (nr == 8) ? ~0ull : ((1ull << (8 * nr)) - 1ull);
      rows <<= (8 * r0);
      clr |= rows & (0x0101010101010101ull * (unsigned long long)colm);
    }
  }
  __shared__ unsigned long long sh[64];
  sh[t] = clr;
  __syncthreads();
  for (int s = 32; s > 0; s >>= 1) {
    if (t < s) sh[t] |= sh[t + s];
    __syncthreads();
  }
  const unsigned long long live = d[i].mask & ~sh[0];

  // scatter: sources always from the ORIGINAL image (copy already done)
  const int q = t;
  if ((live >> q) & 1ull) {
    const int row = psh + (q >> 3), col = psw + (q & 7);
    #pragma unroll
    for (int c = 0; c < CC; ++c) {
      const int s = d[i].src[c][q];
      const size_t base = (size_t)c * (size_t)HH * (size_t)WW;
      out[base + (size_t)row * WW + (size_t)col] =
          in[base + (size_t)(psh + (s >> 3)) * WW + (size_t)(psw + (s & 7))];
    }
  }
}

extern "C" void kernel_launch(void* const* d_in, const int* in_sizes, int n_in,
                              void* d_out, int out_size, void* d_ws, size_t ws_size,
                              hipStream_t stream) {
  const float* img = (const float*)d_in[0];
  const int* seed = (const int*)d_in[1];
  float* out = (float*)d_out;
  Desc* d = (Desc*)d_ws;   // needs NLOOP*256 = 256 KiB

  const int n4 = (CC * HH * WW) / 4;
  hipLaunchKernelGGL(k_desc_copy, dim3(NLOOP + NCOPY), dim3(256), 0, stream,
                     seed, d, (const vfloat4*)img, (vfloat4*)out, n4);
  hipLaunchKernelGGL(k_live_apply, dim3(NLOOP), dim3(64), 0, stream, img, out, d);
}